// Round 6
// baseline (330.404 us; speedup 1.0000x reference)
//
#include <hip/hip_runtime.h>
#include <hip/hip_bf16.h>

typedef short bf16x8 __attribute__((ext_vector_type(8)));
typedef float f32x4 __attribute__((ext_vector_type(4)));

#define NG   9
#define CIN  1152
#define IG1  128
#define OG1  512
#define IG2  512
#define OG2  128
#define KP   576      // padded K per g2 (9 runs * 64)
#define MT   32       // m-tile per block
#define MTOT 16384
#define HTB  36864    // bytes per ht buffer (32 rows * 72 granules * 16B)
#define OSTRIDE 1156  // epilogue LDS stride (floats)

__device__ __forceinline__ short f2bf(float f) {
    unsigned u = __float_as_uint(f);
    u += 0x7fff + ((u >> 16) & 1);   // RNE
    return (short)(u >> 16);
}
__device__ __forceinline__ short cvt1(float f) {
    __hip_bfloat16 h = __float2bfloat16(f);
    return *reinterpret_cast<short*>(&h);
}

// ---- prep (merged): w1 -> bf16 copy; w2 -> permuted+padded bf16 W2p
__global__ __launch_bounds__(256) void prep(const float* __restrict__ w1, const float* __restrict__ w2,
                                            short* __restrict__ w1b, short* __restrict__ w2p) {
    int i = blockIdx.x * 256 + threadIdx.x;
    const int NW1 = NG * OG1 * IG1;            // 589824
    if (i < NW1) { w1b[i] = f2bf(w1[i]); return; }
    int j = i - NW1;
    if (j >= NG * OG2 * KP) return;            // 663552
    int g2  = j / (OG2 * KP);
    int rem = j - g2 * (OG2 * KP);
    int o2  = rem / KP;
    int kp  = rem - o2 * KP;
    int g1 = kp >> 6, r = kp & 63;
    int olo = (512 * g2 - g1 + 8) / 9;         // ceil((512g2-g1)/9)
    int jj = 9 * (olo + r) + g1 - 512 * g2;    // >= 0 by construction
    float v = (jj < 512) ? w2[(g2 * OG2 + o2) * IG2 + jj] : 0.0f;
    w2p[j] = f2bf(v);
}

// ---- fused v4: 16 waves (1024 thr), MT=32. Per wave: L1 o-slice 32; L2 col-chunks
// [s, s+cnt) of 72 (chunk = 16 out-cols), cnt = 4 (even w) / 5 (odd w).
// One raw barrier per g1; ht double-buffered; acc total <= 128 regs -> 4 waves/SIMD.
__global__ __launch_bounds__(1024, 4) void fused(const float* __restrict__ x,
                                                 const short* __restrict__ w1b, const float* __restrict__ b1,
                                                 const short* __restrict__ w2p, const float* __restrict__ b2,
                                                 float* __restrict__ out) {
    __shared__ __attribute__((aligned(16))) char smem[73984];
    float* outs = (float*)smem;               // epilogue overlay [16][1156] fp32

    const int t = threadIdx.x;
    const int m0 = blockIdx.x * MT;
    const int w = t >> 6, lane = t & 63, lr = lane & 15, lg = lane >> 4;
    const int s = (9 * w) >> 1;               // first col-chunk
    const int cnt5 = (w & 1);                 // odd waves own 5 chunks
    const int g2lo = s >> 3;
    const int g2hi = (g2lo < 8) ? g2lo + 1 : 8;

    // zero both ht buffers once (pad slots stay 0; W2p pads are 0 too)
    {
        int4 z = {0, 0, 0, 0};
#pragma unroll
        for (int i = 0; i < 5; ++i) {
            int idx = i * 1024 + t;
            if (idx < 4608) *(int4*)(smem + idx * 16) = z;
        }
    }

    f32x4 acc2[2][5];                          // [mi][chunk j]
#pragma unroll
    for (int mi = 0; mi < 2; ++mi)
#pragma unroll
        for (int j = 0; j < 5; ++j) acc2[mi][j] = (f32x4){0.f,0.f,0.f,0.f};

    for (int g1 = 0; g1 < NG; ++g1) {
        char* htb = smem + (g1 & 1) * HTB;

        // ---- L1: swapped MFMA (A=W1 rows o, B=x rows m) -> C[o][m]
        f32x4 acc1[2][2];                      // [oi][mi]
#pragma unroll
        for (int oi = 0; oi < 2; ++oi)
#pragma unroll
            for (int mi = 0; mi < 2; ++mi) acc1[oi][mi] = (f32x4){0.f,0.f,0.f,0.f};
#pragma unroll
        for (int kf = 0; kf < 4; ++kf) {
            bf16x8 bx[2];
#pragma unroll
            for (int mi = 0; mi < 2; ++mi) {
                const float* p = x + (size_t)(m0 + mi * 16 + lr) * CIN + g1 * IG1 + kf * 32 + lg * 8;
                float4 v0 = *(const float4*)p;
                float4 v1 = *(const float4*)(p + 4);
                bf16x8 sv;
                sv[0]=cvt1(v0.x); sv[1]=cvt1(v0.y); sv[2]=cvt1(v0.z); sv[3]=cvt1(v0.w);
                sv[4]=cvt1(v1.x); sv[5]=cvt1(v1.y); sv[6]=cvt1(v1.z); sv[7]=cvt1(v1.w);
                bx[mi] = sv;
            }
#pragma unroll
            for (int oi = 0; oi < 2; ++oi) {
                bf16x8 af = *(const bf16x8*)(w1b + ((size_t)(g1 * OG1 + w * 32 + oi * 16 + lr) * IG1 + kf * 32 + lg * 8));
#pragma unroll
                for (int mi = 0; mi < 2; ++mi)
                    acc1[oi][mi] = __builtin_amdgcn_mfma_f32_16x16x32_bf16(af, bx[mi], acc1[oi][mi], 0, 0, 0);
            }
        }

        // ---- hardswish -> ht[g1&1] (swizzled b16 scatter; lane holds 4 consecutive o)
#pragma unroll
        for (int oi = 0; oi < 2; ++oi) {
            int ob = w * 32 + oi * 16 + lg * 4;
            float4 bias = *(const float4*)(b1 + g1 * OG1 + ob);
#pragma unroll
            for (int q = 0; q < 4; ++q) {
                int o  = ob + q;
                int c  = 9 * o + g1;
                int g2 = c >> 9;
                int olo = (512 * g2 - g1 + 8) / 9;
                int hc = g2 * 64 + (o - olo);
#pragma unroll
                for (int mi = 0; mi < 2; ++mi) {
                    int m = mi * 16 + lr;
                    float v = acc1[oi][mi][q] + ((const float*)&bias)[q];
                    v = v * fminf(fmaxf(v + 3.0f, 0.0f), 6.0f) * (1.0f / 6.0f);
                    *(short*)(htb + m * 1152 + (((hc >> 3) ^ (m & 7)) << 4) + (hc & 7) * 2) = cvt1(v);
                }
            }
        }

        // ---- prefetch this g1's w2p fragments (consumed after barrier; raw barrier
        //      keeps them in flight; nothing newer is waited on in between)
        bf16x8 wf[5][2];
#pragma unroll
        for (int j = 0; j < 5; ++j) {
            if (j < 4 || cnt5) {
                int cj = s + j, g2j = cj >> 3, nij = cj & 7;
#pragma unroll
                for (int kf = 0; kf < 2; ++kf)
                    wf[j][kf] = *(const bf16x8*)(w2p + (size_t)(g2j * OG2 + nij * 16 + lr) * KP + g1 * 64 + kf * 32 + lg * 8);
            }
        }

        // ---- LDS-only drain + raw barrier (vmem prefetch NOT drained)
        asm volatile("s_waitcnt lgkmcnt(0)" ::: "memory");
        __builtin_amdgcn_s_barrier();

        // ---- L2 partial: ht A-frags (<=2 g2-runs per wave) x prefetched w2p
#pragma unroll
        for (int kf = 0; kf < 2; ++kf) {
            bf16x8 aLO[2], aHI[2];
#pragma unroll
            for (int mi = 0; mi < 2; ++mi) {
                int m = mi * 16 + lr;
                aLO[mi] = *(const bf16x8*)(htb + m * 1152 + (((g2lo * 8 + kf * 4 + lg) ^ (m & 7)) << 4));
                aHI[mi] = *(const bf16x8*)(htb + m * 1152 + (((g2hi * 8 + kf * 4 + lg) ^ (m & 7)) << 4));
            }
#pragma unroll
            for (int j = 0; j < 5; ++j) {
                if (j < 4 || cnt5) {
                    bool hi = (((s + j) >> 3) != g2lo);
#pragma unroll
                    for (int mi = 0; mi < 2; ++mi) {
                        bf16x8 a = hi ? aHI[mi] : aLO[mi];
                        acc2[mi][j] = __builtin_amdgcn_mfma_f32_16x16x32_bf16(a, wf[j][kf], acc2[mi][j], 0, 0, 0);
                    }
                }
            }
        }
        // no second barrier: next iter writes the other ht buffer (validated r3-r5)
    }

    // ---- output epilogue: 2 half-tiles of 16 rows via LDS, fully-coalesced float4 rows
#pragma unroll
    for (int h = 0; h < 2; ++h) {
        __syncthreads();   // prior ht/outs readers done
#pragma unroll
        for (int j = 0; j < 5; ++j) {
            if (j < 4 || cnt5) {
                int cj = s + j, g2j = cj >> 3;
                int o2 = (cj & 7) * 16 + lr;
                float bias = b2[g2j * OG2 + o2];
                int col = o2 * 9 + g2j;
#pragma unroll
                for (int q = 0; q < 4; ++q)
                    outs[(lg * 4 + q) * OSTRIDE + col] = acc2[h][j][q] + bias;
            }
        }
        __syncthreads();
#pragma unroll
        for (int i = 0; i < 5; ++i) {
            int f4 = i * 1024 + t;            // 16 rows x 288 float4 = 4608
            if (f4 < 4608) {
                int row = f4 / 288, c4 = f4 - row * 288;
                float4 v = *(const float4*)&outs[row * OSTRIDE + c4 * 4];
                *(float4*)&out[(size_t)(m0 + h * 16 + row) * CIN + c4 * 4] = v;
            }
        }
    }
}

extern "C" void kernel_launch(void* const* d_in, const int* in_sizes, int n_in,
                              void* d_out, int out_size, void* d_ws, size_t ws_size,
                              hipStream_t stream) {
    const float* x  = (const float*)d_in[0];
    const float* w1 = (const float*)d_in[1];
    const float* b1 = (const float*)d_in[2];
    const float* w2 = (const float*)d_in[3];
    const float* b2 = (const float*)d_in[4];
    float* out = (float*)d_out;

    short* w1b = (short*)d_ws;                                          // 1,179,648 B
    short* w2p = (short*)((char*)d_ws + (size_t)NG * OG1 * IG1 * 2);    // 1,327,104 B

    const int nprep = NG * OG1 * IG1 + NG * OG2 * KP;                   // 1,253,376
    prep<<<(nprep + 255) / 256, 256, 0, stream>>>(w1, w2, w1b, w2p);
    fused<<<MTOT / MT, 1024, 0, stream>>>(x, w1b, b1, w2p, b2, out);
}

// Round 7
// 266.747 us; speedup vs baseline: 1.2386x; 1.2386x over previous
//
#include <hip/hip_runtime.h>
#include <hip/hip_bf16.h>

typedef short bf16x8 __attribute__((ext_vector_type(8)));
typedef float f32x4 __attribute__((ext_vector_type(4)));

#define NG   9
#define CIN  1152
#define IG1  128
#define OG1  512
#define IG2  512
#define OG2  128
#define KP   576      // padded K per g2 (9 runs * 64)
#define MT   32       // m-tile per block
#define MTOT 16384
#define HTB  36864    // bytes per ht buffer (32 rows * 72 granules * 16B)
#define OSTRIDE 1156  // epilogue LDS stride (floats)

__device__ __forceinline__ short f2bf(float f) {
    unsigned u = __float_as_uint(f);
    u += 0x7fff + ((u >> 16) & 1);   // RNE
    return (short)(u >> 16);
}
__device__ __forceinline__ short cvt1(float f) {
    __hip_bfloat16 h = __float2bfloat16(f);
    return *reinterpret_cast<short*>(&h);
}

// ---- prep (merged): w1 -> bf16 copy; w2 -> permuted+padded bf16 W2p
__global__ __launch_bounds__(256) void prep(const float* __restrict__ w1, const float* __restrict__ w2,
                                            short* __restrict__ w1b, short* __restrict__ w2p) {
    int i = blockIdx.x * 256 + threadIdx.x;
    const int NW1 = NG * OG1 * IG1;            // 589824
    if (i < NW1) { w1b[i] = f2bf(w1[i]); return; }
    int j = i - NW1;
    if (j >= NG * OG2 * KP) return;            // 663552
    int g2  = j / (OG2 * KP);
    int rem = j - g2 * (OG2 * KP);
    int o2  = rem / KP;
    int kp  = rem - o2 * KP;
    int g1 = kp >> 6, r = kp & 63;
    int olo = (512 * g2 - g1 + 8) / 9;         // ceil((512g2-g1)/9)
    int jj = 9 * (olo + r) + g1 - 512 * g2;    // >= 0 by construction
    float v = (jj < 512) ? w2[(g2 * OG2 + o2) * IG2 + jj] : 0.0f;
    w2p[j] = f2bf(v);
}

// ---- fused v5: producer/consumer wave specialization. 1024 thr = 16 waves.
// Waves 0-7 (producers): L1 o-slice [p*64,+64) -> hardswish -> ht[g1&1].
// Waves 8-15 (consumers): L2 col-chunks [9*cw, 9*cw+9) of 72, acc held in regs.
// One raw (lgkmcnt-only) barrier per g1; ht double-buffered (ordering as r3-r6).
// Register budget split by role -> both roles fit 128 regs -> 4 waves/SIMD, no spill.
__global__ __launch_bounds__(1024) void fused(const float* __restrict__ x,
                                              const short* __restrict__ w1b, const float* __restrict__ b1,
                                              const short* __restrict__ w2p, const float* __restrict__ b2,
                                              float* __restrict__ out) {
    __shared__ __attribute__((aligned(16))) char smem[73984];
    float* outs = (float*)smem;               // epilogue overlay [16][1156] fp32

    const int t = threadIdx.x;
    const int m0 = blockIdx.x * MT;
    const int w = t >> 6, lane = t & 63, lr = lane & 15, lg = lane >> 4;

    // zero both ht buffers (pad slots stay 0; W2p pads are 0 too)
    {
        int4 z = {0, 0, 0, 0};
#pragma unroll
        for (int i = 0; i < 5; ++i) {
            int idx = i * 1024 + t;
            if (idx < 4608) *(int4*)(smem + idx * 16) = z;
        }
    }
    __syncthreads();                          // zeros visible to everyone

    const int cw = w - 8;                     // consumer index (valid if w>=8)
    const int c0 = cw * 9;                    // first col-chunk of 72
    const int g2lo = (cw >= 0) ? (c0 >> 3) : 0;
    const int g2hi = g2lo + 1;                // 9 consecutive chunks span exactly 2 g2-runs

    f32x4 acc2[2][9];                         // consumer: [mi][chunk]
#pragma unroll
    for (int mi = 0; mi < 2; ++mi)
#pragma unroll
        for (int j = 0; j < 9; ++j) acc2[mi][j] = (f32x4){0.f,0.f,0.f,0.f};

    if (w < 8) {
        // ================= PRODUCER =================
        const int p = w;
        for (int g1 = 0; g1 < NG; ++g1) {
            char* htb = smem + (g1 & 1) * HTB;

            // L1: swapped MFMA (A=W1 rows o, B=x rows m) -> C[o][m]
            f32x4 acc1[4][2];
#pragma unroll
            for (int oi = 0; oi < 4; ++oi)
#pragma unroll
                for (int mi = 0; mi < 2; ++mi) acc1[oi][mi] = (f32x4){0.f,0.f,0.f,0.f};
#pragma unroll
            for (int kf = 0; kf < 4; ++kf) {
                bf16x8 bx[2];
#pragma unroll
                for (int mi = 0; mi < 2; ++mi) {
                    const float* pp = x + (size_t)(m0 + mi * 16 + lr) * CIN + g1 * IG1 + kf * 32 + lg * 8;
                    float4 v0 = *(const float4*)pp;
                    float4 v1 = *(const float4*)(pp + 4);
                    bf16x8 sv;
                    sv[0]=cvt1(v0.x); sv[1]=cvt1(v0.y); sv[2]=cvt1(v0.z); sv[3]=cvt1(v0.w);
                    sv[4]=cvt1(v1.x); sv[5]=cvt1(v1.y); sv[6]=cvt1(v1.z); sv[7]=cvt1(v1.w);
                    bx[mi] = sv;
                }
#pragma unroll
                for (int oi = 0; oi < 4; ++oi) {
                    bf16x8 af = *(const bf16x8*)(w1b + ((size_t)(g1 * OG1 + p * 64 + oi * 16 + lr) * IG1 + kf * 32 + lg * 8));
#pragma unroll
                    for (int mi = 0; mi < 2; ++mi)
                        acc1[oi][mi] = __builtin_amdgcn_mfma_f32_16x16x32_bf16(af, bx[mi], acc1[oi][mi], 0, 0, 0);
                }
            }

            // hardswish -> ht[g1&1] (swizzled b16 scatter; lane holds 4 consecutive o)
#pragma unroll
            for (int oi = 0; oi < 4; ++oi) {
                int ob = p * 64 + oi * 16 + lg * 4;
                float4 bias = *(const float4*)(b1 + g1 * OG1 + ob);
#pragma unroll
                for (int q = 0; q < 4; ++q) {
                    int o  = ob + q;
                    int c  = 9 * o + g1;
                    int g2 = c >> 9;
                    int olo = (512 * g2 - g1 + 8) / 9;
                    int hc = g2 * 64 + (o - olo);
#pragma unroll
                    for (int mi = 0; mi < 2; ++mi) {
                        int m = mi * 16 + lr;
                        float v = acc1[oi][mi][q] + ((const float*)&bias)[q];
                        v = v * fminf(fmaxf(v + 3.0f, 0.0f), 6.0f) * (1.0f / 6.0f);
                        *(short*)(htb + m * 1152 + (((hc >> 3) ^ (m & 7)) << 4) + (hc & 7) * 2) = cvt1(v);
                    }
                }
            }

            asm volatile("s_waitcnt lgkmcnt(0)" ::: "memory");   // ht writes visible
            __builtin_amdgcn_s_barrier();
        }
    } else {
        // ================= CONSUMER =================
        for (int g1 = 0; g1 < NG; ++g1) {
            char* htb = smem + (g1 & 1) * HTB;

            __builtin_amdgcn_s_barrier();     // wait for ht[g1&1]; prev reads already consumed

#pragma unroll
            for (int kf = 0; kf < 2; ++kf) {
                bf16x8 aLO[2], aHI[2];
#pragma unroll
                for (int mi = 0; mi < 2; ++mi) {
                    int m = mi * 16 + lr;
                    aLO[mi] = *(const bf16x8*)(htb + m * 1152 + (((g2lo * 8 + kf * 4 + lg) ^ (m & 7)) << 4));
                    aHI[mi] = *(const bf16x8*)(htb + m * 1152 + (((g2hi * 8 + kf * 4 + lg) ^ (m & 7)) << 4));
                }
#pragma unroll
                for (int j = 0; j < 9; ++j) {
                    int cj = c0 + j, g2j = cj >> 3, nij = cj & 7;
                    bf16x8 wfj = *(const bf16x8*)(w2p + (size_t)(g2j * OG2 + nij * 16 + lr) * KP + g1 * 64 + kf * 32 + lg * 8);
                    bool hi = (g2j != g2lo);
#pragma unroll
                    for (int mi = 0; mi < 2; ++mi) {
                        bf16x8 a = hi ? aHI[mi] : aLO[mi];
                        acc2[mi][j] = __builtin_amdgcn_mfma_f32_16x16x32_bf16(a, wfj, acc2[mi][j], 0, 0, 0);
                    }
                }
            }
        }
    }

    // ---- output epilogue: 2 half-tiles of 16 rows via LDS, fully-coalesced float4 rows
#pragma unroll
    for (int h = 0; h < 2; ++h) {
        __syncthreads();   // all ht reads done; outs overlay safe
        if (w >= 8) {
#pragma unroll
            for (int j = 0; j < 9; ++j) {
                int cj = c0 + j, g2j = cj >> 3;
                int o2 = (cj & 7) * 16 + lr;
                float bias = b2[g2j * OG2 + o2];
                int col = o2 * 9 + g2j;
#pragma unroll
                for (int q = 0; q < 4; ++q)
                    outs[(lg * 4 + q) * OSTRIDE + col] = acc2[h][j][q] + bias;
            }
        }
        __syncthreads();
#pragma unroll
        for (int i = 0; i < 5; ++i) {
            int f4 = i * 1024 + t;            // 16 rows x 288 float4 = 4608
            if (f4 < 4608) {
                int row = f4 / 288, c4 = f4 - row * 288;
                float4 v = *(const float4*)&outs[row * OSTRIDE + c4 * 4];
                *(float4*)&out[(size_t)(m0 + h * 16 + row) * CIN + c4 * 4] = v;
            }
        }
    }
}

extern "C" void kernel_launch(void* const* d_in, const int* in_sizes, int n_in,
                              void* d_out, int out_size, void* d_ws, size_t ws_size,
                              hipStream_t stream) {
    const float* x  = (const float*)d_in[0];
    const float* w1 = (const float*)d_in[1];
    const float* b1 = (const float*)d_in[2];
    const float* w2 = (const float*)d_in[3];
    const float* b2 = (const float*)d_in[4];
    float* out = (float*)d_out;

    short* w1b = (short*)d_ws;                                          // 1,179,648 B
    short* w2p = (short*)((char*)d_ws + (size_t)NG * OG1 * IG1 * 2);    // 1,327,104 B

    const int nprep = NG * OG1 * IG1 + NG * OG2 * KP;                   // 1,253,376
    prep<<<(nprep + 255) / 256, 256, 0, stream>>>(w1, w2, w1b, w2p);
    fused<<<MTOT / MT, 1024, 0, stream>>>(x, w1b, b1, w2p, b2, out);
}